// Round 9
// baseline (182.805 us; speedup 1.0000x reference)
//
#include <hip/hip_runtime.h>
#include <hip/hip_bf16.h>
#include <hip/hip_fp16.h>
#include <math.h>

#define N_NODES 100000
#define N_EDGES 1600000
#define IN_F    128
#define NH      8
#define HD      8
#define HID     64   // NH*HD
#define NEG_SLOPE 0.2f

#define BSH   5      // fine bucket shift: 32 dst nodes per bucket
#define BSZ   32
#define NBK   3125   // 100000/32 exact (fine buckets)
#define NCB   196    // coarse buckets: ceil(100000/512)
#define CSTR  9216   // coarse bucket stride (mean 8163, +11 sigma)
#define BCAP  832    // LDS edge cap in p2agg (fine bucket, mean 512)
#define NBPJ  782    // proj blocks: ceil(100000/128), 128 nodes/block
#define NPB   160    // partition (pass A) blocks
#define EPB   10000  // edges per partition block (160*10000 = 1.6M exact)
#define GSTR  16     // gcnt stride: one 64B line per coarse bucket

typedef short bf16x8 __attribute__((ext_vector_type(8)));
typedef float f32x4  __attribute__((ext_vector_type(4)));

static __device__ __forceinline__ unsigned short f2bf(float x) {
    __hip_bfloat16 h = __float2bfloat16(x);
    return *(unsigned short*)&h;
}

// ---------------------------------------------------------------------------
// K0 prep: zero gcnt (196 padded lines) + build the 20 KB frag-order B-image.
// ---------------------------------------------------------------------------
__global__ __launch_bounds__(256) void prep_kernel(
    const float* __restrict__ W, const float* __restrict__ a_src,
    const float* __restrict__ a_dst, unsigned short* __restrict__ Bg,
    int* __restrict__ gcnt)
{
    const int tid = threadIdx.x;
    for (int i = blockIdx.x * 256 + tid; i < NCB * GSTR; i += 16 * 256) gcnt[i] = 0;
    if (blockIdx.x != 0) return;

    __shared__ __align__(16) unsigned short bl[10240];
    for (int idx = tid; idx < 128 * 16; idx += 256) {
        const int f = idx >> 4, cq = idx & 15;
        const float4 w = *(const float4*)(W + f * 64 + cq * 4);
        const int kc = f >> 5, q = (f >> 3) & 3, j = f & 7;
        const float wf[4] = {w.x, w.y, w.z, w.w};
        #pragma unroll
        for (int i = 0; i < 4; ++i) {
            const int col = cq * 4 + i;
            bl[(col >> 4) * 2048 + kc * 512 + q * 128 + (col & 15) * 8 + j] = f2bf(wf[i]);
        }
    }
    for (int idx = tid; idx < 128 * 8; idx += 256) {
        const int f = idx >> 3, h = idx & 7;
        const float4 wa = *(const float4*)(W + f * 64 + h * 8);
        const float4 wb = *(const float4*)(W + f * 64 + h * 8 + 4);
        const float4 sa = *(const float4*)(a_src + h * 8);
        const float4 sb = *(const float4*)(a_src + h * 8 + 4);
        const float4 da = *(const float4*)(a_dst + h * 8);
        const float4 db = *(const float4*)(a_dst + h * 8 + 4);
        float esv = fmaf(wa.x, sa.x, fmaf(wa.y, sa.y, fmaf(wa.z, sa.z,
                    fmaf(wa.w, sa.w, fmaf(wb.x, sb.x, fmaf(wb.y, sb.y,
                    fmaf(wb.z, sb.z, wb.w * sb.w)))))));
        float edv = fmaf(wa.x, da.x, fmaf(wa.y, da.y, fmaf(wa.z, da.z,
                    fmaf(wa.w, da.w, fmaf(wb.x, db.x, fmaf(wb.y, db.y,
                    fmaf(wb.z, db.z, wb.w * db.w)))))));
        const int kc = f >> 5, q = (f >> 3) & 3, j = f & 7;
        bl[4 * 2048 + kc * 512 + q * 128 + h * 8 + j]       = f2bf(esv);
        bl[4 * 2048 + kc * 512 + q * 128 + (8 + h) * 8 + j] = f2bf(edv);
    }
    __syncthreads();
    for (int idx = tid; idx < 1280; idx += 256)
        ((uint4*)Bg)[idx] = ((const uint4*)bl)[idx];
}

// ---------------------------------------------------------------------------
// K1 (fused, 512 threads): blocks [0,NBPJ) = MFMA projection; blocks
// [NBPJ,NBPJ+NPB) = radix pass A into 196 coarse buckets (dst>>9).
// Unchanged from round 8 (passed; out of top-5).
// ---------------------------------------------------------------------------
__global__ __launch_bounds__(512) void fused_pp_kernel(
    const float* __restrict__ vert, const unsigned short* __restrict__ Bg,
    __hip_bfloat16* __restrict__ gb, float* __restrict__ es, float* __restrict__ ed,
    const int* __restrict__ edge, int* __restrict__ gcnt,
    unsigned int* __restrict__ packed)
{
    __shared__ __align__(16) char smem[28672];   // 28 KB
    const int tid = threadIdx.x;

    if (blockIdx.x < NBPJ) {
        // =================== proj branch ===================
        unsigned short* b_lds = (unsigned short*)smem;   // [0, 20480)
        const int nbeg = blockIdx.x * 128;
        const int lane = tid & 63, wv = tid >> 6;
        const int mn   = lane & 15, quad = lane >> 4;

        for (int idx = tid; idx < 1280; idx += 512)
            *(uint4*)(smem + idx * 16) = ((const uint4*)Bg)[idx];

        const int row = nbeg + wv * 16 + mn;
        bf16x8 afr[4];
        #pragma unroll
        for (int kc = 0; kc < 4; ++kc) {
            float4 p = make_float4(0.f, 0.f, 0.f, 0.f);
            float4 q4 = make_float4(0.f, 0.f, 0.f, 0.f);
            if (row < N_NODES) {
                const float* rp = vert + (size_t)row * IN_F + kc * 32 + quad * 8;
                p  = *(const float4*)rp;
                q4 = *(const float4*)(rp + 4);
            }
            bf16x8 a;
            a[0] = (short)f2bf(p.x);  a[1] = (short)f2bf(p.y);
            a[2] = (short)f2bf(p.z);  a[3] = (short)f2bf(p.w);
            a[4] = (short)f2bf(q4.x); a[5] = (short)f2bf(q4.y);
            a[6] = (short)f2bf(q4.z); a[7] = (short)f2bf(q4.w);
            afr[kc] = a;
        }
        __syncthreads();

        const unsigned short* bbase = b_lds + quad * 128 + mn * 8;
        f32x4 acc[5];
        #pragma unroll
        for (int c = 0; c < 5; ++c) acc[c] = (f32x4){0.f, 0.f, 0.f, 0.f};
        #pragma unroll
        for (int kc = 0; kc < 4; ++kc) {
            #pragma unroll
            for (int c = 0; c < 5; ++c) {
                const bf16x8 bfr = *(const bf16x8*)(bbase + c * 2048 + kc * 512);
                acc[c] = __builtin_amdgcn_mfma_f32_16x16x32_bf16(afr[kc], bfr, acc[c], 0, 0, 0);
            }
        }
        __syncthreads();

        unsigned short* gl = (unsigned short*)smem + wv * 1152;   // 16 x 72 shorts
        float* lesd = (float*)(smem + 18432) + wv * 320;          // 2 x 16 x 10 floats
        #pragma unroll
        for (int c = 0; c < 4; ++c)
            #pragma unroll
            for (int r = 0; r < 4; ++r)
                gl[(quad * 4 + r) * 72 + c * 16 + mn] = f2bf(acc[c][r]);
        {
            float* dst = (mn < 8) ? (lesd + mn) : (lesd + 160 + (mn - 8));
            #pragma unroll
            for (int r = 0; r < 4; ++r) dst[(quad * 4 + r) * 10] = acc[4][r];
        }
        __syncthreads();
        {
            const int row2 = lane >> 2, part = lane & 3;
            const int node = nbeg + wv * 16 + row2;
            if (node < N_NODES) {
                const uint4* sp = (const uint4*)(gl + row2 * 72 + part * 16);
                *(uint4*)((unsigned short*)gb + (size_t)node * HID + part * 16) = sp[0];
                *(uint4*)((unsigned short*)gb + (size_t)node * HID + part * 16 + 8) = sp[1];
            }
        }
        {
            const int nl = lane >> 2, h2 = (lane & 3) * 2;
            const int node = nbeg + wv * 16 + nl;
            if (node < N_NODES) {
                *(float2*)(es + node * NH + h2) = *(const float2*)(lesd + nl * 10 + h2);
                *(float2*)(ed + node * NH + h2) = *(const float2*)(lesd + 160 + nl * 10 + h2);
            }
        }
    } else {
        // =================== radix pass A (coarse, 196 buckets) ===========
        int* lh    = (int*)smem;                // 784 B
        int* lbase = (int*)(smem + 1024);       // 784 B
        const int pb = blockIdx.x - NBPJ;

        if (tid < NCB) lh[tid] = 0;
        __syncthreads();
        const int4* src4 = (const int4*)(edge + pb * EPB);
        const int4* dst4 = (const int4*)(edge + N_EDGES + pb * EPB);
        for (int t = tid; t < EPB / 4; t += 512) {
            const int4 d = dst4[t];
            atomicAdd(&lh[d.x >> 9], 1);
            atomicAdd(&lh[d.y >> 9], 1);
            atomicAdd(&lh[d.z >> 9], 1);
            atomicAdd(&lh[d.w >> 9], 1);
        }
        __syncthreads();
        if (tid < NCB) {
            const int c = lh[tid];
            lbase[tid] = c ? (tid * CSTR + atomicAdd(&gcnt[tid * GSTR], c)) : 0;
            lh[tid] = 0;                        // reuse as local cursor
        }
        __syncthreads();
        for (int t = tid; t < EPB / 4; t += 512) {
            const int4 s = src4[t];
            const int4 d = dst4[t];
            int bk, pos;
            bk = d.x >> 9; pos = min(lbase[bk] + atomicAdd(&lh[bk], 1), NCB * CSTR - 1);
            packed[pos] = ((unsigned)s.x << 9) | (unsigned)(d.x & 511);
            bk = d.y >> 9; pos = min(lbase[bk] + atomicAdd(&lh[bk], 1), NCB * CSTR - 1);
            packed[pos] = ((unsigned)s.y << 9) | (unsigned)(d.y & 511);
            bk = d.z >> 9; pos = min(lbase[bk] + atomicAdd(&lh[bk], 1), NCB * CSTR - 1);
            packed[pos] = ((unsigned)s.z << 9) | (unsigned)(d.z & 511);
            bk = d.w >> 9; pos = min(lbase[bk] + atomicAdd(&lh[bk], 1), NCB * CSTR - 1);
            packed[pos] = ((unsigned)s.w << 9) | (unsigned)(d.w & 511);
        }
    }
}

// ---------------------------------------------------------------------------
// K2 radix pass B — round 9: FULL dst-sort (512-way counting sort, same
// pass count as the old 16-way), direct scattered write-back into the
// block-private L2-resident region (staging copy dropped), and per-NODE
// (start,count) emitted. p2agg's CSR build becomes unnecessary.
// ---------------------------------------------------------------------------
__global__ __launch_bounds__(512) void radixb_kernel(
    const int* __restrict__ gcnt, unsigned int* __restrict__ packed,
    int2* __restrict__ nodeinfo)
{
    __shared__ unsigned int ebuf[CSTR];    // 36,864 B
    __shared__ int fh[512], fpre[512];     // 4 KB
    __shared__ int wsum[8];
    const int tid = threadIdx.x;
    const int cb  = blockIdx.x;
    const int cnt = min(gcnt[cb * GSTR], CSTR);
    unsigned int* in = packed + (size_t)cb * CSTR;

    fh[tid] = 0;
    __syncthreads();
    for (int i = tid; i < cnt; i += 512) {
        const unsigned v = in[i];
        ebuf[i] = v;
        atomicAdd(&fh[v & 511], 1);
    }
    __syncthreads();
    {   // block-wide exclusive scan over 512 counters
        const int lane = tid & 63, wv = tid >> 6;
        const int v = fh[tid];
        int s = v;
        #pragma unroll
        for (int off = 1; off < 64; off <<= 1) {
            const int t = __shfl_up(s, off, 64);
            if (lane >= off) s += t;
        }
        if (lane == 63) wsum[wv] = s;
        __syncthreads();
        if (tid < 8) {
            const int w = wsum[tid];
            int e = w;
            #pragma unroll
            for (int off = 1; off < 8; off <<= 1) {
                const int t = __shfl_up(e, off, 64);
                if (tid >= off) e += t;
            }
            wsum[tid] = e - w;
        }
        __syncthreads();
        const int ex = s - v + wsum[wv];
        fpre[tid] = ex;
        fh[tid]   = ex;                    // cursor
    }
    __syncthreads();
    for (int i = tid; i < cnt; i += 512) {
        const unsigned v = ebuf[i];
        const int pos = atomicAdd(&fh[v & 511], 1);
        in[pos] = ((v >> 9) << 7) | (v & 31);   // (src<<7) | (dst&31)
    }
    __syncthreads();
    const int node = cb * 512 + tid;
    if (node < N_NODES)
        nodeinfo[node] = make_int2(cb * CSTR + fpre[tid], fh[tid] - fpre[tid]);
}

// ---------------------------------------------------------------------------
// K5 — round 9: CSR build DELETED (edges arrive dst-sorted; segments from
// nodeinfo). Phase A: coalesced global read of packed -> ssrt + fp16 pexp.
// Phase B: 16 lanes/edge x 4 cols, dwordx2 gather (1 VMEM per 4 edges),
// combine via shfl_xor(16)+shfl_xor(32), float4 row store.
// ---------------------------------------------------------------------------
__global__ __launch_bounds__(256) void p2agg_kernel(
    const int2* __restrict__ nodeinfo, const unsigned int* __restrict__ packed,
    const unsigned short* __restrict__ gb, const float* __restrict__ es,
    const float* __restrict__ ed, float* __restrict__ out)
{
    __shared__ unsigned int ssrt[BCAP];                       // 3328 B
    __shared__ __align__(16) unsigned short pexp[BCAP * 8];   // 13312 B fp16
    __shared__ int sbeg[BSZ + 1];
    __shared__ __align__(16) float led[BSZ * NH];             // 1 KB (~17.8 KB tot)

    const int tid  = threadIdx.x;
    const int b    = blockIdx.x;
    const int nbeg = b << BSH;
    const int ebase = nodeinfo[nbeg].x;

    if (tid < BSZ) {
        const int2 ni = nodeinfo[nbeg + tid];
        sbeg[tid] = ni.x - ebase;
        if (tid == BSZ - 1) sbeg[BSZ] = ni.x + ni.y - ebase;
    }
    for (int i = tid; i < BSZ * NH; i += 256) led[i] = ed[nbeg * NH + i];
    __syncthreads();

    const int ecnt = min(sbeg[BSZ], BCAP);

    // ---- phase A: coalesced edge read + batched exp-scores -> fp16 ----
    for (int i = tid; i < ecnt; i += 256) {
        const unsigned pw = packed[ebase + i];
        ssrt[i] = pw;
        const int src = (int)(pw >> 7), dl = (int)(pw & (BSZ - 1));
        const float4 e0 = *(const float4*)(es + (size_t)src * NH);
        const float4 e1 = *(const float4*)(es + (size_t)src * NH + 4);
        const float4 l0 = *(const float4*)(led + dl * NH);
        const float4 l1 = *(const float4*)(led + dl * NH + 4);
        float s[8] = {e0.x + l0.x, e0.y + l0.y, e0.z + l0.z, e0.w + l0.w,
                      e1.x + l1.x, e1.y + l1.y, e1.z + l1.z, e1.w + l1.w};
        #pragma unroll
        for (int k = 0; k < 8; ++k)
            s[k] = __expf(fmaxf(s[k], s[k] * NEG_SLOPE));
        __half2 h01 = __floats2half2_rn(s[0], s[1]);
        __half2 h23 = __floats2half2_rn(s[2], s[3]);
        __half2 h45 = __floats2half2_rn(s[4], s[5]);
        __half2 h67 = __floats2half2_rn(s[6], s[7]);
        uint4 w;
        w.x = *(unsigned*)&h01; w.y = *(unsigned*)&h23;
        w.z = *(unsigned*)&h45; w.w = *(unsigned*)&h67;
        *(uint4*)(pexp + i * 8) = w;
    }
    __syncthreads();

    // ---- phase B: aggregation, 16 lanes/edge x 4 cols ----
    const int lane = tid & 63;
    const int wv   = tid >> 6;
    const int c4   = lane & 15;          // col group: cols 4*c4 .. 4*c4+3
    const int eg   = lane >> 4;          // edge slot 0..3
    const int h    = c4 >> 1;            // head of this col group
    const unsigned c4_8 = (unsigned)(c4 << 3);
    const char* gbase = (const char*)gb;

#define GSTEP(B)                                                              \
    {                                                                         \
        const int e = (B) + eg;                                               \
        const unsigned pw = ssrt[e];                                          \
        const float pe = __half2float(*(const __half*)(pexp + (e << 3) + h)); \
        const unsigned voff = (pw & ~127u) | c4_8;                            \
        const uint2 gu = *(const uint2*)(gbase + voff);                       \
        a0 = fmaf(pe, __uint_as_float(gu.x << 16), a0);                       \
        a1 = fmaf(pe, __uint_as_float(gu.x & 0xFFFF0000u), a1);               \
        a2 = fmaf(pe, __uint_as_float(gu.y << 16), a2);                       \
        a3 = fmaf(pe, __uint_as_float(gu.y & 0xFFFF0000u), a3);               \
        l += pe;                                                              \
    }

    for (int n = wv; n < BSZ; n += 4) {
        const int beg = min(sbeg[n], ecnt);
        const int end = min(sbeg[n + 1], ecnt);
        float l = 0.f, a0 = 0.f, a1 = 0.f, a2 = 0.f, a3 = 0.f;
        int i = beg;
        for (; i + 8 <= end; i += 8) { GSTEP(i) GSTEP(i + 4) }
        for (; i < end; i += 4) {                    // masked tail group
            const int e  = i + eg;
            const int ec = min(e, end - 1);
            const unsigned pw = ssrt[ec];
            float pe = __half2float(*(const __half*)(pexp + (ec << 3) + h));
            pe = (e < end) ? pe : 0.f;
            const unsigned voff = (pw & ~127u) | c4_8;
            const uint2 gu = *(const uint2*)(gbase + voff);
            a0 = fmaf(pe, __uint_as_float(gu.x << 16), a0);
            a1 = fmaf(pe, __uint_as_float(gu.x & 0xFFFF0000u), a1);
            a2 = fmaf(pe, __uint_as_float(gu.y << 16), a2);
            a3 = fmaf(pe, __uint_as_float(gu.y & 0xFFFF0000u), a3);
            l += pe;
        }
        l  += __shfl_xor(l, 16);  l  += __shfl_xor(l, 32);
        a0 += __shfl_xor(a0, 16); a0 += __shfl_xor(a0, 32);
        a1 += __shfl_xor(a1, 16); a1 += __shfl_xor(a1, 32);
        a2 += __shfl_xor(a2, 16); a2 += __shfl_xor(a2, 32);
        a3 += __shfl_xor(a3, 16); a3 += __shfl_xor(a3, 32);
        if (eg == 0) {
            const float rl = 1.f / fmaxf(l, 1e-16f);
            float o0 = a0 * rl, o1 = a1 * rl, o2 = a2 * rl, o3 = a3 * rl;
            o0 = (o0 > 0.f) ? o0 : (__expf(o0) - 1.f);   // ELU
            o1 = (o1 > 0.f) ? o1 : (__expf(o1) - 1.f);
            o2 = (o2 > 0.f) ? o2 : (__expf(o2) - 1.f);
            o3 = (o3 > 0.f) ? o3 : (__expf(o3) - 1.f);
            *(float4*)(out + (size_t)(nbeg + n) * HID + c4 * 4) =
                make_float4(o0, o1, o2, o3);
        }
    }
#undef GSTEP
}

// ---------------------------------------------------------------------------
extern "C" void kernel_launch(void* const* d_in, const int* in_sizes, int n_in,
                              void* d_out, int out_size, void* d_ws, size_t ws_size,
                              hipStream_t stream)
{
    const float* vert  = (const float*)d_in[0];
    const int*   edge  = (const int*)  d_in[1];
    const float* W     = (const float*)d_in[2];
    const float* a_src = (const float*)d_in[3];
    const float* a_dst = (const float*)d_in[4];
    float* out = (float*)d_out;

    char* ws = (char*)d_ws;
    __hip_bfloat16* gb     = (__hip_bfloat16*)(ws);            // 12,800,000 B
    float*          es     = (float*)(ws + 12800000);          //  3,200,000 B
    float*          ed     = (float*)(ws + 16000000);          //  3,200,000 B
    unsigned int*   packed = (unsigned int*)(ws + 19200000);   //  7,225,344 B (NCB*CSTR*4)
    int*            gcnt   = (int*)(ws + 26425344);            //     12,544 B
    int2*           nodeinfo = (int2*)(ws + 26437888);         //    800,000 B
    unsigned short* Bg     = (unsigned short*)(ws + 27237888); //     20,480 B (27.26 MB tot)

    prep_kernel<<<16, 256, 0, stream>>>(W, a_src, a_dst, Bg, gcnt);
    fused_pp_kernel<<<NBPJ + NPB, 512, 0, stream>>>(
        vert, Bg, gb, es, ed, edge, gcnt, packed);
    radixb_kernel<<<NCB, 512, 0, stream>>>(gcnt, packed, nodeinfo);
    p2agg_kernel<<<NBK, 256, 0, stream>>>(nodeinfo, packed, (const unsigned short*)gb, es, ed, out);
}

// Round 10
// 175.656 us; speedup vs baseline: 1.0407x; 1.0407x over previous
//
#include <hip/hip_runtime.h>
#include <hip/hip_bf16.h>
#include <hip/hip_fp16.h>
#include <math.h>

#define N_NODES 100000
#define N_EDGES 1600000
#define IN_F    128
#define NH      8
#define HD      8
#define HID     64   // NH*HD
#define NEG_SLOPE 0.2f

#define BSH   5      // fine bucket shift: 32 dst nodes per bucket
#define BSZ   32
#define NBK   3125   // 100000/32 exact (fine buckets)
#define NCB   196    // coarse buckets: ceil(100000/512)
#define CSTR  9216   // coarse bucket stride (mean 8163, +11 sigma)
#define BCAP  832    // LDS edge cap in p2agg (fine bucket, mean 512)
#define NBPJ  782    // proj blocks: ceil(100000/128), 128 nodes/block
#define NPB   160    // partition (pass A) blocks
#define EPB   10000  // edges per partition block (160*10000 = 1.6M exact)
#define GSTR  16     // gcnt stride: one 64B line per coarse bucket

typedef short bf16x8 __attribute__((ext_vector_type(8)));
typedef float f32x4  __attribute__((ext_vector_type(4)));

static __device__ __forceinline__ unsigned short f2bf(float x) {
    __hip_bfloat16 h = __float2bfloat16(x);
    return *(unsigned short*)&h;
}

// ---------------------------------------------------------------------------
// K0 prep: zero gcnt (196 padded lines) + build the 20 KB frag-order B-image.
// ---------------------------------------------------------------------------
__global__ __launch_bounds__(256) void prep_kernel(
    const float* __restrict__ W, const float* __restrict__ a_src,
    const float* __restrict__ a_dst, unsigned short* __restrict__ Bg,
    int* __restrict__ gcnt)
{
    const int tid = threadIdx.x;
    for (int i = blockIdx.x * 256 + tid; i < NCB * GSTR; i += 16 * 256) gcnt[i] = 0;
    if (blockIdx.x != 0) return;

    __shared__ __align__(16) unsigned short bl[10240];
    for (int idx = tid; idx < 128 * 16; idx += 256) {
        const int f = idx >> 4, cq = idx & 15;
        const float4 w = *(const float4*)(W + f * 64 + cq * 4);
        const int kc = f >> 5, q = (f >> 3) & 3, j = f & 7;
        const float wf[4] = {w.x, w.y, w.z, w.w};
        #pragma unroll
        for (int i = 0; i < 4; ++i) {
            const int col = cq * 4 + i;
            bl[(col >> 4) * 2048 + kc * 512 + q * 128 + (col & 15) * 8 + j] = f2bf(wf[i]);
        }
    }
    for (int idx = tid; idx < 128 * 8; idx += 256) {
        const int f = idx >> 3, h = idx & 7;
        const float4 wa = *(const float4*)(W + f * 64 + h * 8);
        const float4 wb = *(const float4*)(W + f * 64 + h * 8 + 4);
        const float4 sa = *(const float4*)(a_src + h * 8);
        const float4 sb = *(const float4*)(a_src + h * 8 + 4);
        const float4 da = *(const float4*)(a_dst + h * 8);
        const float4 db = *(const float4*)(a_dst + h * 8 + 4);
        float esv = fmaf(wa.x, sa.x, fmaf(wa.y, sa.y, fmaf(wa.z, sa.z,
                    fmaf(wa.w, sa.w, fmaf(wb.x, sb.x, fmaf(wb.y, sb.y,
                    fmaf(wb.z, sb.z, wb.w * sb.w)))))));
        float edv = fmaf(wa.x, da.x, fmaf(wa.y, da.y, fmaf(wa.z, da.z,
                    fmaf(wa.w, da.w, fmaf(wb.x, db.x, fmaf(wb.y, db.y,
                    fmaf(wb.z, db.z, wb.w * db.w)))))));
        const int kc = f >> 5, q = (f >> 3) & 3, j = f & 7;
        bl[4 * 2048 + kc * 512 + q * 128 + h * 8 + j]       = f2bf(esv);
        bl[4 * 2048 + kc * 512 + q * 128 + (8 + h) * 8 + j] = f2bf(edv);
    }
    __syncthreads();
    for (int idx = tid; idx < 1280; idx += 256)
        ((uint4*)Bg)[idx] = ((const uint4*)bl)[idx];
}

// ---------------------------------------------------------------------------
// K1 (fused, 512 threads): blocks [0,NBPJ) = MFMA projection; blocks
// [NBPJ,NBPJ+NPB) = radix pass A into 196 coarse buckets (dst>>9).
// Unchanged (round-8-proven).
// ---------------------------------------------------------------------------
__global__ __launch_bounds__(512) void fused_pp_kernel(
    const float* __restrict__ vert, const unsigned short* __restrict__ Bg,
    __hip_bfloat16* __restrict__ gb, float* __restrict__ es, float* __restrict__ ed,
    const int* __restrict__ edge, int* __restrict__ gcnt,
    unsigned int* __restrict__ packed)
{
    __shared__ __align__(16) char smem[28672];   // 28 KB
    const int tid = threadIdx.x;

    if (blockIdx.x < NBPJ) {
        // =================== proj branch ===================
        unsigned short* b_lds = (unsigned short*)smem;   // [0, 20480)
        const int nbeg = blockIdx.x * 128;
        const int lane = tid & 63, wv = tid >> 6;
        const int mn   = lane & 15, quad = lane >> 4;

        for (int idx = tid; idx < 1280; idx += 512)
            *(uint4*)(smem + idx * 16) = ((const uint4*)Bg)[idx];

        const int row = nbeg + wv * 16 + mn;
        bf16x8 afr[4];
        #pragma unroll
        for (int kc = 0; kc < 4; ++kc) {
            float4 p = make_float4(0.f, 0.f, 0.f, 0.f);
            float4 q4 = make_float4(0.f, 0.f, 0.f, 0.f);
            if (row < N_NODES) {
                const float* rp = vert + (size_t)row * IN_F + kc * 32 + quad * 8;
                p  = *(const float4*)rp;
                q4 = *(const float4*)(rp + 4);
            }
            bf16x8 a;
            a[0] = (short)f2bf(p.x);  a[1] = (short)f2bf(p.y);
            a[2] = (short)f2bf(p.z);  a[3] = (short)f2bf(p.w);
            a[4] = (short)f2bf(q4.x); a[5] = (short)f2bf(q4.y);
            a[6] = (short)f2bf(q4.z); a[7] = (short)f2bf(q4.w);
            afr[kc] = a;
        }
        __syncthreads();

        const unsigned short* bbase = b_lds + quad * 128 + mn * 8;
        f32x4 acc[5];
        #pragma unroll
        for (int c = 0; c < 5; ++c) acc[c] = (f32x4){0.f, 0.f, 0.f, 0.f};
        #pragma unroll
        for (int kc = 0; kc < 4; ++kc) {
            #pragma unroll
            for (int c = 0; c < 5; ++c) {
                const bf16x8 bfr = *(const bf16x8*)(bbase + c * 2048 + kc * 512);
                acc[c] = __builtin_amdgcn_mfma_f32_16x16x32_bf16(afr[kc], bfr, acc[c], 0, 0, 0);
            }
        }
        __syncthreads();

        unsigned short* gl = (unsigned short*)smem + wv * 1152;   // 16 x 72 shorts
        float* lesd = (float*)(smem + 18432) + wv * 320;          // 2 x 16 x 10 floats
        #pragma unroll
        for (int c = 0; c < 4; ++c)
            #pragma unroll
            for (int r = 0; r < 4; ++r)
                gl[(quad * 4 + r) * 72 + c * 16 + mn] = f2bf(acc[c][r]);
        {
            float* dst = (mn < 8) ? (lesd + mn) : (lesd + 160 + (mn - 8));
            #pragma unroll
            for (int r = 0; r < 4; ++r) dst[(quad * 4 + r) * 10] = acc[4][r];
        }
        __syncthreads();
        {
            const int row2 = lane >> 2, part = lane & 3;
            const int node = nbeg + wv * 16 + row2;
            if (node < N_NODES) {
                const uint4* sp = (const uint4*)(gl + row2 * 72 + part * 16);
                *(uint4*)((unsigned short*)gb + (size_t)node * HID + part * 16) = sp[0];
                *(uint4*)((unsigned short*)gb + (size_t)node * HID + part * 16 + 8) = sp[1];
            }
        }
        {
            const int nl = lane >> 2, h2 = (lane & 3) * 2;
            const int node = nbeg + wv * 16 + nl;
            if (node < N_NODES) {
                *(float2*)(es + node * NH + h2) = *(const float2*)(lesd + nl * 10 + h2);
                *(float2*)(ed + node * NH + h2) = *(const float2*)(lesd + 160 + nl * 10 + h2);
            }
        }
    } else {
        // =================== radix pass A (coarse, 196 buckets) ===========
        int* lh    = (int*)smem;                // 784 B
        int* lbase = (int*)(smem + 1024);       // 784 B
        const int pb = blockIdx.x - NBPJ;

        if (tid < NCB) lh[tid] = 0;
        __syncthreads();
        const int4* src4 = (const int4*)(edge + pb * EPB);
        const int4* dst4 = (const int4*)(edge + N_EDGES + pb * EPB);
        for (int t = tid; t < EPB / 4; t += 512) {
            const int4 d = dst4[t];
            atomicAdd(&lh[d.x >> 9], 1);
            atomicAdd(&lh[d.y >> 9], 1);
            atomicAdd(&lh[d.z >> 9], 1);
            atomicAdd(&lh[d.w >> 9], 1);
        }
        __syncthreads();
        if (tid < NCB) {
            const int c = lh[tid];
            lbase[tid] = c ? (tid * CSTR + atomicAdd(&gcnt[tid * GSTR], c)) : 0;
            lh[tid] = 0;                        // reuse as local cursor
        }
        __syncthreads();
        for (int t = tid; t < EPB / 4; t += 512) {
            const int4 s = src4[t];
            const int4 d = dst4[t];
            int bk, pos;
            bk = d.x >> 9; pos = min(lbase[bk] + atomicAdd(&lh[bk], 1), NCB * CSTR - 1);
            packed[pos] = ((unsigned)s.x << 9) | (unsigned)(d.x & 511);
            bk = d.y >> 9; pos = min(lbase[bk] + atomicAdd(&lh[bk], 1), NCB * CSTR - 1);
            packed[pos] = ((unsigned)s.y << 9) | (unsigned)(d.y & 511);
            bk = d.z >> 9; pos = min(lbase[bk] + atomicAdd(&lh[bk], 1), NCB * CSTR - 1);
            packed[pos] = ((unsigned)s.z << 9) | (unsigned)(d.z & 511);
            bk = d.w >> 9; pos = min(lbase[bk] + atomicAdd(&lh[bk], 1), NCB * CSTR - 1);
            packed[pos] = ((unsigned)s.w << 9) | (unsigned)(d.w & 511);
        }
    }
}

// ---------------------------------------------------------------------------
// K2 radix pass B — round 10: 1024 threads (grid is 196 blocks -> was
// grid-occupancy-limited at 8 waves/CU; 16 waves halves the serial passes).
// Full dst-sort (512-way counting sort), direct write-back, nodeinfo emit.
// ---------------------------------------------------------------------------
__global__ __launch_bounds__(1024) void radixb_kernel(
    const int* __restrict__ gcnt, unsigned int* __restrict__ packed,
    int2* __restrict__ nodeinfo)
{
    __shared__ unsigned int ebuf[CSTR];    // 36,864 B
    __shared__ int fh[512], fpre[512];     // 4 KB
    __shared__ int wsum[8];
    const int tid = threadIdx.x;
    const int cb  = blockIdx.x;
    const int cnt = min(gcnt[cb * GSTR], CSTR);
    unsigned int* in = packed + (size_t)cb * CSTR;

    if (tid < 512) fh[tid] = 0;
    __syncthreads();
    for (int i = tid; i < cnt; i += 1024) {
        const unsigned v = in[i];
        ebuf[i] = v;
        atomicAdd(&fh[v & 511], 1);
    }
    __syncthreads();
    // block-wide exclusive scan over 512 counters (first 8 waves)
    int s = 0, v = 0;
    {
        const int lane = tid & 63, wvv = tid >> 6;
        if (tid < 512) {
            v = fh[tid];
            s = v;
            #pragma unroll
            for (int off = 1; off < 64; off <<= 1) {
                const int t = __shfl_up(s, off, 64);
                if (lane >= off) s += t;
            }
            if (lane == 63) wsum[wvv] = s;
        }
        __syncthreads();
        if (tid < 8) {
            const int w = wsum[tid];
            int e = w;
            #pragma unroll
            for (int off = 1; off < 8; off <<= 1) {
                const int t = __shfl_up(e, off, 64);
                if (tid >= off) e += t;
            }
            wsum[tid] = e - w;
        }
        __syncthreads();
        if (tid < 512) {
            const int ex = s - v + wsum[wvv];
            fpre[tid] = ex;
            fh[tid]   = ex;                // cursor
        }
    }
    __syncthreads();
    for (int i = tid; i < cnt; i += 1024) {
        const unsigned vv = ebuf[i];
        const int pos = atomicAdd(&fh[vv & 511], 1);
        in[pos] = ((vv >> 9) << 7) | (vv & 31);   // (src<<7) | (dst&31)
    }
    __syncthreads();
    if (tid < 512) {
        const int node = cb * 512 + tid;
        if (node < N_NODES)
            nodeinfo[node] = make_int2(cb * CSTR + fpre[tid], fh[tid] - fpre[tid]);
    }
}

// ---------------------------------------------------------------------------
// K5 — round 10: phase B re-batched for MLP: 16 edges per step with 4
// INDEPENDENT uint2 gathers issued before any consuming fmaf (in-flight
// lines 2 -> 4; round 9 showed latency-bound: VALU cut didn't move dur).
// Remainder = one masked 16-wide batch (clamped idx, pe=0 pads; pad
// gathers hit a resident line). Rest unchanged from round 9.
// ---------------------------------------------------------------------------
__global__ __launch_bounds__(256) void p2agg_kernel(
    const int2* __restrict__ nodeinfo, const unsigned int* __restrict__ packed,
    const unsigned short* __restrict__ gb, const float* __restrict__ es,
    const float* __restrict__ ed, float* __restrict__ out)
{
    __shared__ unsigned int ssrt[BCAP];                       // 3328 B
    __shared__ __align__(16) unsigned short pexp[BCAP * 8];   // 13312 B fp16
    __shared__ int sbeg[BSZ + 1];
    __shared__ __align__(16) float led[BSZ * NH];             // 1 KB (~17.8 KB tot)

    const int tid  = threadIdx.x;
    const int b    = blockIdx.x;
    const int nbeg = b << BSH;
    const int ebase = nodeinfo[nbeg].x;

    if (tid < BSZ) {
        const int2 ni = nodeinfo[nbeg + tid];
        sbeg[tid] = ni.x - ebase;
        if (tid == BSZ - 1) sbeg[BSZ] = ni.x + ni.y - ebase;
    }
    for (int i = tid; i < BSZ * NH; i += 256) led[i] = ed[nbeg * NH + i];
    __syncthreads();

    const int ecnt = min(sbeg[BSZ], BCAP);

    // ---- phase A: coalesced edge read + batched exp-scores -> fp16 ----
    for (int i = tid; i < ecnt; i += 256) {
        const unsigned pw = packed[ebase + i];
        ssrt[i] = pw;
        const int src = (int)(pw >> 7), dl = (int)(pw & (BSZ - 1));
        const float4 e0 = *(const float4*)(es + (size_t)src * NH);
        const float4 e1 = *(const float4*)(es + (size_t)src * NH + 4);
        const float4 l0 = *(const float4*)(led + dl * NH);
        const float4 l1 = *(const float4*)(led + dl * NH + 4);
        float s[8] = {e0.x + l0.x, e0.y + l0.y, e0.z + l0.z, e0.w + l0.w,
                      e1.x + l1.x, e1.y + l1.y, e1.z + l1.z, e1.w + l1.w};
        #pragma unroll
        for (int k = 0; k < 8; ++k)
            s[k] = __expf(fmaxf(s[k], s[k] * NEG_SLOPE));
        __half2 h01 = __floats2half2_rn(s[0], s[1]);
        __half2 h23 = __floats2half2_rn(s[2], s[3]);
        __half2 h45 = __floats2half2_rn(s[4], s[5]);
        __half2 h67 = __floats2half2_rn(s[6], s[7]);
        uint4 w;
        w.x = *(unsigned*)&h01; w.y = *(unsigned*)&h23;
        w.z = *(unsigned*)&h45; w.w = *(unsigned*)&h67;
        *(uint4*)(pexp + i * 8) = w;
    }
    __syncthreads();

    // ---- phase B: aggregation, 16 lanes/edge x 4 cols, 4 gathers in flight
    const int lane = tid & 63;
    const int wv   = tid >> 6;
    const int c4   = lane & 15;          // col group: cols 4*c4 .. 4*c4+3
    const int eg   = lane >> 4;          // edge slot 0..3
    const int h    = c4 >> 1;            // head of this col group
    const unsigned c4_8 = (unsigned)(c4 << 3);
    const char* gbase = (const char*)gb;

    for (int n = wv; n < BSZ; n += 4) {
        const int end = min(sbeg[n + 1], ecnt);
        const int beg = min(sbeg[n], end);
        float l = 0.f, a0 = 0.f, a1 = 0.f, a2 = 0.f, a3 = 0.f;
        int i = beg;
        for (; i + 16 <= end; i += 16) {             // bulk: 4 gathers in flight
            const unsigned pw0 = ssrt[i + eg];
            const unsigned pw1 = ssrt[i + 4 + eg];
            const unsigned pw2 = ssrt[i + 8 + eg];
            const unsigned pw3 = ssrt[i + 12 + eg];
            const uint2 g0 = *(const uint2*)(gbase + ((pw0 & ~127u) | c4_8));
            const uint2 g1 = *(const uint2*)(gbase + ((pw1 & ~127u) | c4_8));
            const uint2 g2 = *(const uint2*)(gbase + ((pw2 & ~127u) | c4_8));
            const uint2 g3 = *(const uint2*)(gbase + ((pw3 & ~127u) | c4_8));
            const float pe0 = __half2float(*(const __half*)(pexp + ((i + eg) << 3) + h));
            const float pe1 = __half2float(*(const __half*)(pexp + ((i + 4 + eg) << 3) + h));
            const float pe2 = __half2float(*(const __half*)(pexp + ((i + 8 + eg) << 3) + h));
            const float pe3 = __half2float(*(const __half*)(pexp + ((i + 12 + eg) << 3) + h));
            a0 = fmaf(pe0, __uint_as_float(g0.x << 16), a0);
            a1 = fmaf(pe0, __uint_as_float(g0.x & 0xFFFF0000u), a1);
            a2 = fmaf(pe0, __uint_as_float(g0.y << 16), a2);
            a3 = fmaf(pe0, __uint_as_float(g0.y & 0xFFFF0000u), a3);
            a0 = fmaf(pe1, __uint_as_float(g1.x << 16), a0);
            a1 = fmaf(pe1, __uint_as_float(g1.x & 0xFFFF0000u), a1);
            a2 = fmaf(pe1, __uint_as_float(g1.y << 16), a2);
            a3 = fmaf(pe1, __uint_as_float(g1.y & 0xFFFF0000u), a3);
            a0 = fmaf(pe2, __uint_as_float(g2.x << 16), a0);
            a1 = fmaf(pe2, __uint_as_float(g2.x & 0xFFFF0000u), a1);
            a2 = fmaf(pe2, __uint_as_float(g2.y << 16), a2);
            a3 = fmaf(pe2, __uint_as_float(g2.y & 0xFFFF0000u), a3);
            a0 = fmaf(pe3, __uint_as_float(g3.x << 16), a0);
            a1 = fmaf(pe3, __uint_as_float(g3.x & 0xFFFF0000u), a1);
            a2 = fmaf(pe3, __uint_as_float(g3.y << 16), a2);
            a3 = fmaf(pe3, __uint_as_float(g3.y & 0xFFFF0000u), a3);
            l += (pe0 + pe1) + (pe2 + pe3);
        }
        if (i < end) {                               // one masked 16-wide batch
            const int e0 = i + eg, e1 = i + 4 + eg, e2 = i + 8 + eg, e3 = i + 12 + eg;
            const int ec0 = min(e0, end - 1), ec1 = min(e1, end - 1);
            const int ec2 = min(e2, end - 1), ec3 = min(e3, end - 1);
            const unsigned pw0 = ssrt[ec0];
            const unsigned pw1 = ssrt[ec1];
            const unsigned pw2 = ssrt[ec2];
            const unsigned pw3 = ssrt[ec3];
            const uint2 g0 = *(const uint2*)(gbase + ((pw0 & ~127u) | c4_8));
            const uint2 g1 = *(const uint2*)(gbase + ((pw1 & ~127u) | c4_8));
            const uint2 g2 = *(const uint2*)(gbase + ((pw2 & ~127u) | c4_8));
            const uint2 g3 = *(const uint2*)(gbase + ((pw3 & ~127u) | c4_8));
            float pe0 = __half2float(*(const __half*)(pexp + (ec0 << 3) + h));
            float pe1 = __half2float(*(const __half*)(pexp + (ec1 << 3) + h));
            float pe2 = __half2float(*(const __half*)(pexp + (ec2 << 3) + h));
            float pe3 = __half2float(*(const __half*)(pexp + (ec3 << 3) + h));
            pe0 = (e0 < end) ? pe0 : 0.f;
            pe1 = (e1 < end) ? pe1 : 0.f;
            pe2 = (e2 < end) ? pe2 : 0.f;
            pe3 = (e3 < end) ? pe3 : 0.f;
            a0 = fmaf(pe0, __uint_as_float(g0.x << 16), a0);
            a1 = fmaf(pe0, __uint_as_float(g0.x & 0xFFFF0000u), a1);
            a2 = fmaf(pe0, __uint_as_float(g0.y << 16), a2);
            a3 = fmaf(pe0, __uint_as_float(g0.y & 0xFFFF0000u), a3);
            a0 = fmaf(pe1, __uint_as_float(g1.x << 16), a0);
            a1 = fmaf(pe1, __uint_as_float(g1.x & 0xFFFF0000u), a1);
            a2 = fmaf(pe1, __uint_as_float(g1.y << 16), a2);
            a3 = fmaf(pe1, __uint_as_float(g1.y & 0xFFFF0000u), a3);
            a0 = fmaf(pe2, __uint_as_float(g2.x << 16), a0);
            a1 = fmaf(pe2, __uint_as_float(g2.x & 0xFFFF0000u), a1);
            a2 = fmaf(pe2, __uint_as_float(g2.y << 16), a2);
            a3 = fmaf(pe2, __uint_as_float(g2.y & 0xFFFF0000u), a3);
            a0 = fmaf(pe3, __uint_as_float(g3.x << 16), a0);
            a1 = fmaf(pe3, __uint_as_float(g3.x & 0xFFFF0000u), a1);
            a2 = fmaf(pe3, __uint_as_float(g3.y << 16), a2);
            a3 = fmaf(pe3, __uint_as_float(g3.y & 0xFFFF0000u), a3);
            l += (pe0 + pe1) + (pe2 + pe3);
        }
        l  += __shfl_xor(l, 16);  l  += __shfl_xor(l, 32);
        a0 += __shfl_xor(a0, 16); a0 += __shfl_xor(a0, 32);
        a1 += __shfl_xor(a1, 16); a1 += __shfl_xor(a1, 32);
        a2 += __shfl_xor(a2, 16); a2 += __shfl_xor(a2, 32);
        a3 += __shfl_xor(a3, 16); a3 += __shfl_xor(a3, 32);
        if (eg == 0) {
            const float rl = 1.f / fmaxf(l, 1e-16f);
            float o0 = a0 * rl, o1 = a1 * rl, o2 = a2 * rl, o3 = a3 * rl;
            o0 = (o0 > 0.f) ? o0 : (__expf(o0) - 1.f);   // ELU
            o1 = (o1 > 0.f) ? o1 : (__expf(o1) - 1.f);
            o2 = (o2 > 0.f) ? o2 : (__expf(o2) - 1.f);
            o3 = (o3 > 0.f) ? o3 : (__expf(o3) - 1.f);
            *(float4*)(out + (size_t)(nbeg + n) * HID + c4 * 4) =
                make_float4(o0, o1, o2, o3);
        }
    }
}

// ---------------------------------------------------------------------------
extern "C" void kernel_launch(void* const* d_in, const int* in_sizes, int n_in,
                              void* d_out, int out_size, void* d_ws, size_t ws_size,
                              hipStream_t stream)
{
    const float* vert  = (const float*)d_in[0];
    const int*   edge  = (const int*)  d_in[1];
    const float* W     = (const float*)d_in[2];
    const float* a_src = (const float*)d_in[3];
    const float* a_dst = (const float*)d_in[4];
    float* out = (float*)d_out;

    char* ws = (char*)d_ws;
    __hip_bfloat16* gb     = (__hip_bfloat16*)(ws);            // 12,800,000 B
    float*          es     = (float*)(ws + 12800000);          //  3,200,000 B
    float*          ed     = (float*)(ws + 16000000);          //  3,200,000 B
    unsigned int*   packed = (unsigned int*)(ws + 19200000);   //  7,225,344 B (NCB*CSTR*4)
    int*            gcnt   = (int*)(ws + 26425344);            //     12,544 B
    int2*           nodeinfo = (int2*)(ws + 26437888);         //    800,000 B
    unsigned short* Bg     = (unsigned short*)(ws + 27237888); //     20,480 B (27.26 MB tot)

    prep_kernel<<<16, 256, 0, stream>>>(W, a_src, a_dst, Bg, gcnt);
    fused_pp_kernel<<<NBPJ + NPB, 512, 0, stream>>>(
        vert, Bg, gb, es, ed, edge, gcnt, packed);
    radixb_kernel<<<NCB, 1024, 0, stream>>>(gcnt, packed, nodeinfo);
    p2agg_kernel<<<NBK, 256, 0, stream>>>(nodeinfo, packed, (const unsigned short*)gb, es, ed, out);
}